// Round 1
// baseline (2668.478 us; speedup 1.0000x reference)
//
#include <hip/hip_runtime.h>
#include <hip/hip_bf16.h>
#include <cstdint>
#include <cstddef>

namespace {

constexpr int kB = 2, kLF = 64, kFEAT = 80, kH = 64, kSKIP = 256, kA = 256;
constexpr int kNL = 24, kUPK = 4, kT4 = 256;   // LF*UPK upsampled coarse frames
constexpr int kS = 19200;                      // signal length
constexpr int kNS = kB * kS;                   // 38400 flattened (b,t)
constexpr int k2H = 128;

// ---------------- cond: ConvTranspose1d(k=stride=4) + 1x1 cond conv ----------------
// cond[b][og(3072)][t4(256)]; layer i uses rows i*128..i*128+127, time index t/75.
__global__ void cond_kernel(const float* __restrict__ lf, const float* __restrict__ tw,
                            const float* __restrict__ tb, const float* __restrict__ cw,
                            const float* __restrict__ cb, float* __restrict__ cond) {
  const int t4 = blockIdx.x, b = blockIdx.y;
  const int ifr = t4 >> 2, kk = t4 & 3;
  __shared__ float up[kFEAT];
  const int tid = threadIdx.x;  // 128
  if (tid < kFEAT) {
    float s = tb[tid];
    const float* lfp = lf + (b * kLF + ifr) * kFEAT;
    for (int c = 0; c < kFEAT; ++c) s += lfp[c] * tw[(c * kFEAT + tid) * kUPK + kk];
    up[tid] = s;
  }
  __syncthreads();
  for (int r = 0; r < 24; ++r) {
    const int o = r * 128 + tid;
    const float* wr = cw + o * kFEAT;
    float s = cb[o];
    for (int c = 0; c < kFEAT; ++c) s += wr[c] * up[c];
    cond[((size_t)b * 3072 + o) * kT4 + t4] = s;
  }
}

__global__ void bias_sum_kernel(const float* __restrict__ sb, float* __restrict__ bs) {
  const int o = threadIdx.x;  // 256
  float s = 0.f;
  for (int i = 0; i < kNL; ++i) s += sb[i * kSKIP + o];
  bs[o] = s;
}

__global__ void embed_kernel(const float* __restrict__ sig, const float* __restrict__ ew,
                             const float* __restrict__ eb, float* __restrict__ x) {
  const int idx = blockIdx.x * 256 + threadIdx.x;
  if (idx >= kB * kH * kS) return;
  const int t = idx % kS;
  const int bh = idx / kS;
  const int h = bh % kH, b = bh / kH;
  x[idx] = sig[b * kS + t] * ew[h] + eb[h];
}

// ---------------- one residual layer ----------------
// block: (t-tile of 64, b). threads 256 = (tx in [0,16) time, oy in [0,16) chan).
// y[o,t] = sum_h W[o,h,0]*x[h,t-d] + W[o,h,1]*x[h,t] + db[o] + cond; g = tanh*sigm;
// x' = res_w @ g + res_b + x ; g written to global as bf16 for the skip GEMM.
__global__ __launch_bounds__(256) void layer_kernel(
    const float* __restrict__ x_in, float* __restrict__ x_out,
    __hip_bfloat16* __restrict__ g_out, const float* __restrict__ Wd,
    const float* __restrict__ db, const float* __restrict__ cond,
    const float* __restrict__ Wr, const float* __restrict__ rb,
    int layer, int d, int write_x, int grow_base) {
  const int b = blockIdx.y;
  const int t0 = blockIdx.x * 64;
  __shared__ float xc[kH][64];
  __shared__ float xp[kH][64];  // reused as g after the conv GEMM
  const int tid = threadIdx.x;
  const int tx = tid & 15, oy = tid >> 4;
  const float* xb = x_in + (size_t)b * kH * kS;
  for (int r = 0; r < 4; ++r) {  // stage x[t0..t0+63], vectorized
    const int f4 = r * 256 + tid;
    const int h = f4 >> 4, c4 = (f4 & 15) << 2;
    *reinterpret_cast<float4*>(&xc[h][c4]) =
        *reinterpret_cast<const float4*>(xb + h * kS + t0 + c4);
  }
  for (int r = 0; r < 16; ++r) {  // stage x[t0-d..], scalar (unaligned + left pad)
    const int f = r * 256 + tid;
    const int h = f >> 6, c = f & 63;
    const int src = t0 - d + c;
    xp[h][c] = (src >= 0) ? xb[h * kS + src] : 0.f;
  }
  __syncthreads();
  float accL[4][4] = {{0.f}}, accH[4][4] = {{0.f}};
  for (int hin = 0; hin < kH; ++hin) {
    float bc[4], bp[4];
    *reinterpret_cast<float4*>(bc) = *reinterpret_cast<const float4*>(&xc[hin][tx * 4]);
    *reinterpret_cast<float4*>(bp) = *reinterpret_cast<const float4*>(&xp[hin][tx * 4]);
#pragma unroll
    for (int j = 0; j < 4; ++j) {
      const int olo = oy * 4 + j;
      const float2 wl = *reinterpret_cast<const float2*>(Wd + (olo * kH + hin) * 2);
      const float2 wh = *reinterpret_cast<const float2*>(Wd + ((olo + kH) * kH + hin) * 2);
#pragma unroll
      for (int jt = 0; jt < 4; ++jt) {
        accL[j][jt] += wl.x * bp[jt] + wl.y * bc[jt];
        accH[j][jt] += wh.x * bp[jt] + wh.y * bc[jt];
      }
    }
  }
  __syncthreads();  // all reads of xp done before overwriting with g
  const float* condp = cond + ((size_t)b * 3072 + layer * k2H) * kT4;
#pragma unroll
  for (int j = 0; j < 4; ++j) {
    const int olo = oy * 4 + j;
#pragma unroll
    for (int jt = 0; jt < 4; ++jt) {
      const int t = tx * 4 + jt, tg = t0 + t;
      const int c75 = tg / 75;
      const float ylo = accL[j][jt] + db[olo] + condp[olo * kT4 + c75];
      const float yhi = accH[j][jt] + db[olo + kH] + condp[(olo + kH) * kT4 + c75];
      const float g = tanhf(ylo) * (1.f / (1.f + expf(-yhi)));
      xp[olo][t] = g;
      g_out[((size_t)(grow_base + olo)) * kNS + b * kS + tg] = __float2bfloat16(g);
    }
  }
  __syncthreads();
  if (write_x) {
    float accr[4][4] = {{0.f}};
    for (int hh = 0; hh < kH; ++hh) {
      float gv[4];
      *reinterpret_cast<float4*>(gv) = *reinterpret_cast<const float4*>(&xp[hh][tx * 4]);
#pragma unroll
      for (int j = 0; j < 4; ++j) {
        const float w = Wr[(oy * 4 + j) * kH + hh];
#pragma unroll
        for (int jt = 0; jt < 4; ++jt) accr[j][jt] += w * gv[jt];
      }
    }
#pragma unroll
    for (int j = 0; j < 4; ++j) {
      const int h = oy * 4 + j;
#pragma unroll
      for (int jt = 0; jt < 4; ++jt) {
        const int t = tx * 4 + jt;
        x_out[((size_t)b * kH + h) * kS + t0 + t] = accr[j][jt] + rb[h] + xc[h][t];
      }
    }
  }
}

// ---------------- stacked skip projection ----------------
// skip[o][n] (+)= sum over layers l0..l0+nl-1, h: skip_w[l][o][h] * g[(l-l0)*64+h][n]
__global__ __launch_bounds__(256) void skip_gemm_kernel(
    const __hip_bfloat16* __restrict__ g_all, const float* __restrict__ sw,
    const float* __restrict__ bs, float* __restrict__ skip, int l0, int nl, int first) {
  const int n0 = blockIdx.x * 128, o0 = blockIdx.y * 128;
  __shared__ float Asm[128][65];              // +1 pad: conflict-free column reads
  __shared__ __hip_bfloat162 Bsm[64][64];     // g chunk, bf16 pairs
  const int tid = threadIdx.x;
  const int tx = tid & 15, oy = tid >> 4;
  float acc[8][8] = {{0.f}};
  for (int lc = 0; lc < nl; ++lc) {
    const int l = l0 + lc;
    for (int r = 0; r < 32; ++r) {
      const int f = r * 256 + tid;
      const int o = f >> 6, h = f & 63;
      Asm[o][h] = sw[((size_t)(l * kSKIP + o0 + o)) * kH + h];
    }
    for (int r = 0; r < 8; ++r) {
      const int f4 = r * 256 + tid;
      const int h = f4 >> 5, c4 = (f4 & 31) << 2;
      const uint2 raw = *reinterpret_cast<const uint2*>(
          g_all + ((size_t)(lc * kH + h)) * kNS + n0 + c4);
      *reinterpret_cast<uint2*>(&Bsm[h][c4 >> 1]) = raw;
    }
    __syncthreads();
    for (int k = 0; k < kH; ++k) {
      float bv[8];
      const __hip_bfloat162* brow = &Bsm[k][tx * 4];
#pragma unroll
      for (int q = 0; q < 4; ++q) {
        const __hip_bfloat162 v = brow[q];
        bv[2 * q] = __bfloat162float(v.x);
        bv[2 * q + 1] = __bfloat162float(v.y);
      }
#pragma unroll
      for (int j = 0; j < 8; ++j) {
        const float a = Asm[oy * 8 + j][k];
#pragma unroll
        for (int jn = 0; jn < 8; ++jn) acc[j][jn] += a * bv[jn];
      }
    }
    __syncthreads();
  }
#pragma unroll
  for (int j = 0; j < 8; ++j) {
    const int o = o0 + oy * 8 + j;
#pragma unroll
    for (int jn = 0; jn < 8; ++jn) {
      const int n = n0 + tx * 8 + jn;
      const size_t idx = (size_t)o * kNS + n;
      skip[idx] = acc[j][jn] + (first ? bs[o] : skip[idx]);
    }
  }
}

// ---------------- output head: relu -> 256x256 -> relu -> 256x256 -> log_softmax ----
__global__ __launch_bounds__(256) void head_kernel(const float* __restrict__ skip,
                                                   const float* __restrict__ W1,
                                                   const float* __restrict__ W2,
                                                   float* __restrict__ out) {
  const int n0 = blockIdx.x * 64;
  __shared__ float sm[256][64];
  const int tid = threadIdx.x;
  const int tx = tid & 7, oy = tid >> 3;
  for (int r = 0; r < 16; ++r) {
    const int f4 = r * 256 + tid;
    const int o = f4 >> 4, c4 = (f4 & 15) << 2;
    float4 v = *reinterpret_cast<const float4*>(skip + (size_t)o * kNS + n0 + c4);
    v.x = fmaxf(v.x, 0.f); v.y = fmaxf(v.y, 0.f);
    v.z = fmaxf(v.z, 0.f); v.w = fmaxf(v.w, 0.f);
    *reinterpret_cast<float4*>(&sm[o][c4]) = v;
  }
  __syncthreads();
  float acc[8][8];
#pragma unroll
  for (int j = 0; j < 8; ++j)
#pragma unroll
    for (int jn = 0; jn < 8; ++jn) acc[j][jn] = 0.f;
  for (int k = 0; k < 256; ++k) {
    float bv[8];
    *reinterpret_cast<float4*>(bv) = *reinterpret_cast<const float4*>(&sm[k][tx * 8]);
    *reinterpret_cast<float4*>(bv + 4) = *reinterpret_cast<const float4*>(&sm[k][tx * 8 + 4]);
#pragma unroll
    for (int j = 0; j < 8; ++j) {
      const float a = W1[(oy * 8 + j) * 256 + k];
#pragma unroll
      for (int jn = 0; jn < 8; ++jn) acc[j][jn] += a * bv[jn];
    }
  }
  __syncthreads();
#pragma unroll
  for (int j = 0; j < 8; ++j)
#pragma unroll
    for (int jn = 0; jn < 8; ++jn) sm[oy * 8 + j][tx * 8 + jn] = fmaxf(acc[j][jn], 0.f);
  __syncthreads();
#pragma unroll
  for (int j = 0; j < 8; ++j)
#pragma unroll
    for (int jn = 0; jn < 8; ++jn) acc[j][jn] = 0.f;
  for (int k = 0; k < 256; ++k) {
    float bv[8];
    *reinterpret_cast<float4*>(bv) = *reinterpret_cast<const float4*>(&sm[k][tx * 8]);
    *reinterpret_cast<float4*>(bv + 4) = *reinterpret_cast<const float4*>(&sm[k][tx * 8 + 4]);
#pragma unroll
    for (int j = 0; j < 8; ++j) {
      const float a = W2[(oy * 8 + j) * 256 + k];
#pragma unroll
      for (int jn = 0; jn < 8; ++jn) acc[j][jn] += a * bv[jn];
    }
  }
  __syncthreads();
#pragma unroll
  for (int j = 0; j < 8; ++j)
#pragma unroll
    for (int jn = 0; jn < 8; ++jn) sm[oy * 8 + j][tx * 8 + jn] = acc[j][jn];
  __syncthreads();
  // log_softmax over the 256 channels of each column; 4 threads per column
  const int c = tid >> 2, rr = tid & 3;
  float m = -3.4e38f;
  for (int q = rr; q < 256; q += 4) m = fmaxf(m, sm[q][c]);
  m = fmaxf(m, __shfl_xor(m, 1));
  m = fmaxf(m, __shfl_xor(m, 2));
  float ssum = 0.f;
  for (int q = rr; q < 256; q += 4) ssum += expf(sm[q][c] - m);
  ssum += __shfl_xor(ssum, 1);
  ssum += __shfl_xor(ssum, 2);
  const float lse = m + logf(ssum);
  const int n = n0 + c;
  const int bb = n / kS, t = n - bb * kS;
  float* op = out + (size_t)bb * kA * kS + t;
  for (int q = rr; q < 256; q += 4) op[(size_t)q * kS] = sm[q][c] - lse;
}

}  // namespace

extern "C" void kernel_launch(void* const* d_in, const int* in_sizes, int n_in,
                              void* d_out, int out_size, void* d_ws, size_t ws_size,
                              hipStream_t stream) {
  const float* lf  = (const float*)d_in[0];
  const float* sig = (const float*)d_in[1];
  const float* ew  = (const float*)d_in[2];
  const float* eb  = (const float*)d_in[3];
  const float* tw  = (const float*)d_in[4];
  const float* tb  = (const float*)d_in[5];
  const float* cw  = (const float*)d_in[6];
  const float* cb  = (const float*)d_in[7];
  const float* dw  = (const float*)d_in[8];
  const float* db  = (const float*)d_in[9];
  const float* rw  = (const float*)d_in[10];
  const float* rb  = (const float*)d_in[11];
  const float* sw  = (const float*)d_in[12];
  const float* sb  = (const float*)d_in[13];
  const float* w1  = (const float*)d_in[14];
  const float* w2  = (const float*)d_in[15];
  float* out = (float*)d_out;

  char* p = (char*)d_ws;
  float* cond = (float*)p; p += (size_t)2 * 3072 * 256 * 4;   // 6.29 MB
  float* xA   = (float*)p; p += (size_t)2 * 64 * 19200 * 4;   // 9.83 MB
  float* xB   = (float*)p; p += (size_t)2 * 64 * 19200 * 4;   // 9.83 MB
  float* skip = (float*)p; p += (size_t)256 * 38400 * 4;      // 39.3 MB
  float* bs   = (float*)p; p += 1024;
  __hip_bfloat16* gbuf = (__hip_bfloat16*)p;
  const size_t base = (size_t)(p - (char*)d_ws);
  const size_t per_layer_g = (size_t)64 * 38400 * 2;          // 4.92 MB
  int GL = 1;
  if (ws_size > base) {
    size_t gl = (ws_size - base) / per_layer_g;
    GL = (int)(gl < 1 ? 1 : (gl > 24 ? 24 : gl));
  }

  cond_kernel<<<dim3(256, 2), 128, 0, stream>>>(lf, tw, tb, cw, cb, cond);
  bias_sum_kernel<<<1, 256, 0, stream>>>(sb, bs);
  embed_kernel<<<(2 * 64 * 19200 + 255) / 256, 256, 0, stream>>>(sig, ew, eb, xA);

  float* xcur = xA;
  float* xnxt = xB;
  for (int p0 = 0; p0 < kNL; p0 += GL) {
    const int nl = (kNL - p0 < GL) ? (kNL - p0) : GL;
    for (int lc = 0; lc < nl; ++lc) {
      const int li = p0 + lc;
      const int d = 1 << (li % 6);
      const int wx = (li < kNL - 1) ? 1 : 0;
      layer_kernel<<<dim3(300, 2), 256, 0, stream>>>(
          xcur, xnxt, gbuf, dw + (size_t)li * 128 * 64 * 2, db + li * 128, cond,
          rw + (size_t)(wx ? li : 0) * 64 * 64, rb + (size_t)(wx ? li : 0) * 64,
          li, d, wx, lc * 64);
      if (wx) { float* tmp = xcur; xcur = xnxt; xnxt = tmp; }
    }
    skip_gemm_kernel<<<dim3(300, 2), 256, 0, stream>>>(gbuf, sw, bs, skip, p0, nl, p0 == 0);
  }
  head_kernel<<<600, 256, 0, stream>>>(skip, w1, w2, out);
}

// Round 4
// 658.961 us; speedup vs baseline: 4.0495x; 4.0495x over previous
//
#include <hip/hip_runtime.h>
#include <hip/hip_bf16.h>
#include <cstdint>
#include <cstddef>

namespace {

constexpr int kB = 2, kLF = 64, kFEAT = 80, kH = 64, kSKIP = 256, kA = 256;
constexpr int kNL = 24, kUPK = 4, kT4 = 256;
constexpr int kS = 19200;
constexpr int kGR = 64;                 // guard rows (zero history) per batch
constexpr int kXR = kGR + kS;           // 19264 rows per batch in x buffers
constexpr int kK = kNL * kH;            // 1536 skip K
constexpr int kP = 88;                  // LDS row stride (ushorts): 176B, 16B-aligned

typedef __attribute__((ext_vector_type(8))) short bf8_t;   // 8 x bf16
typedef __attribute__((ext_vector_type(4))) float f4_t;    // 4 x f32

__device__ inline unsigned short f2bu(float f) {
  __hip_bfloat16 h = __float2bfloat16(f);
  return __builtin_bit_cast(unsigned short, h);
}

// ---------------- prep: convert weights to bf16 / transposed layouts ----------------
__global__ void prep_kernel(const float* __restrict__ dw, const float* __restrict__ rw,
                            const float* __restrict__ sw, const float* __restrict__ w1,
                            const float* __restrict__ w2, unsigned short* __restrict__ wcb,
                            unsigned short* __restrict__ wrb, unsigned short* __restrict__ swb,
                            unsigned short* __restrict__ w1b, unsigned short* __restrict__ w2b) {
  int idx = blockIdx.x * 256 + threadIdx.x;
  const int n0 = kNL * 2 * 128 * 64;   // 393216
  const int n1 = (kNL - 1) * 64 * 64;  // 94208
  const int n2 = 256 * kK;             // 393216
  const int n3 = 65536;
  if (idx < n0) {
    int r = idx;
    const int l = r / 16384; r -= l * 16384;
    const int tap = r / 8192; r -= tap * 8192;
    const int o = r / 64; const int h = r - o * 64;
    wcb[idx] = f2bu(dw[((l * 128 + o) * 64 + h) * 2 + tap]);
    return;
  }
  idx -= n0;
  if (idx < n1) { wrb[idx] = f2bu(rw[idx]); return; }
  idx -= n1;
  if (idx < n2) {
    const int o = idx / kK, k = idx - o * kK;
    const int l = k >> 6, h = k & 63;
    swb[idx] = f2bu(sw[(l * 256 + o) * 64 + h]);
    return;
  }
  idx -= n2;
  if (idx < n3) { w1b[idx] = f2bu(w1[idx]); return; }
  idx -= n3;
  if (idx < n3) { w2b[idx] = f2bu(w2[idx]); }
}

// ---------------- cond (with dilate_b folded in) ----------------
__global__ void cond_kernel(const float* __restrict__ lf, const float* __restrict__ tw,
                            const float* __restrict__ tb, const float* __restrict__ cw,
                            const float* __restrict__ cb, const float* __restrict__ dbf,
                            float* __restrict__ cond) {
  const int t4 = blockIdx.x, b = blockIdx.y;
  const int ifr = t4 >> 2, kk = t4 & 3;
  __shared__ float up[kFEAT];
  const int tid = threadIdx.x;  // 128
  if (tid < kFEAT) {
    float s = tb[tid];
    const float* lfp = lf + (b * kLF + ifr) * kFEAT;
    for (int c = 0; c < kFEAT; ++c) s += lfp[c] * tw[(c * kFEAT + tid) * kUPK + kk];
    up[tid] = s;
  }
  __syncthreads();
  for (int r = 0; r < 24; ++r) {
    const int o = r * 128 + tid;
    const float* wr = cw + o * kFEAT;
    float s = cb[o] + dbf[o];
    for (int c = 0; c < kFEAT; ++c) s += wr[c] * up[c];
    cond[((size_t)b * 3072 + o) * kT4 + t4] = s;
  }
}

__global__ void bias_sum_kernel(const float* __restrict__ sb, float* __restrict__ bs) {
  const int o = threadIdx.x;  // 256
  float s = 0.f;
  for (int i = 0; i < kNL; ++i) s += sb[i * kSKIP + o];
  bs[o] = s;
}

// ---------------- embed: x0[b][gr+t][h] transposed fp32, zero guards in both bufs ----
__global__ void embed_kernel(const float* __restrict__ sig, const float* __restrict__ ew,
                             const float* __restrict__ eb, float* __restrict__ xA,
                             float* __restrict__ xB) {
  const int idx = blockIdx.x * 256 + threadIdx.x;
  if (idx >= kB * kXR * kH) return;
  const int h = idx & 63;
  const int row = (idx >> 6) % kXR;
  const int b = idx / (kXR * kH);
  if (row < kGR) {
    xA[idx] = 0.f;
    xB[idx] = 0.f;
  } else {
    const int t = row - kGR;
    xA[idx] = sig[b * kS + t] * ew[h] + eb[h];
  }
}

// ---------------- residual layer, MFMA ----------------
// block: 64-t tile x batch. 4 waves, wave n-slice = 16 t-cols, M=128 per wave.
__global__ __launch_bounds__(256) void layer_kernel(
    const float* __restrict__ x_in, float* __restrict__ x_out,
    const unsigned short* __restrict__ wcb,  // this layer [2][128][64]
    const unsigned short* __restrict__ wrb,  // this layer [64][64]
    const float* __restrict__ cond, const float* __restrict__ rb,
    unsigned short* __restrict__ gbuf, int layer, int d, int write_x) {
  const int b = blockIdx.y;
  const int t0 = blockIdx.x * 64;
  const int tid = threadIdx.x;
  const int lane = tid & 63, wv = tid >> 6;
  const int l15 = lane & 15, l4 = lane >> 4;
  const int nw = wv * 16;

  __shared__ unsigned short Wc[128][kP];
  __shared__ unsigned short xw[64][kP];
  __shared__ float xf[64][68];
  __shared__ unsigned short gt[64][kP];
  __shared__ unsigned short Wr[64][kP];
  __shared__ float cnd[128][2];

  // cond slice: rows layer*128.., cols c0/c0+1
  const int c0 = t0 / 75;
  {
    const int o = tid >> 1, ci = tid & 1;
    int cc = c0 + ci; if (cc > 255) cc = 255;
    cnd[o][ci] = cond[((size_t)b * 3072 + layer * 128 + o) * kT4 + cc];
  }
  if (write_x) {
    for (int r = 0; r < 4; ++r) {
      const int f4 = r * 256 + tid;
      const int row = f4 >> 4, c4 = (f4 & 15) << 2;
      *reinterpret_cast<uint2*>(&Wr[row][c4]) =
          *reinterpret_cast<const uint2*>(wrb + row * 64 + c4);
    }
  }
  // stage rows n: fp32 -> xf, bf16 -> xw (current tap). 64 rows x 16 chunks = 1024.
  const float* xbase = x_in + ((size_t)b * kXR + kGR + t0) * 64;
  for (int r = 0; r < 4; ++r) {
    const int f4 = r * 256 + tid;
    const int row = f4 >> 4, c4 = (f4 & 15) << 2;
    const float4 v = *reinterpret_cast<const float4*>(xbase + row * 64 + c4);
    *reinterpret_cast<float4*>(&xf[row][c4]) = v;
    uint2 pp;
    pp.x = (unsigned)f2bu(v.x) | ((unsigned)f2bu(v.y) << 16);
    pp.y = (unsigned)f2bu(v.z) | ((unsigned)f2bu(v.w) << 16);
    *reinterpret_cast<uint2*>(&xw[row][c4]) = pp;
  }
  // Wc tap1 (current): 128 rows x 16 chunks = 2048.
  for (int r = 0; r < 8; ++r) {
    const int f4 = r * 256 + tid;
    const int row = f4 >> 4, c4 = (f4 & 15) << 2;
    *reinterpret_cast<uint2*>(&Wc[row][c4]) =
        *reinterpret_cast<const uint2*>(wcb + 8192 + row * 64 + c4);
  }
  __syncthreads();

  f4_t acc[8];
#pragma unroll
  for (int i = 0; i < 8; ++i) acc[i] = (f4_t){0.f, 0.f, 0.f, 0.f};
#pragma unroll
  for (int kk = 0; kk < 2; ++kk) {
    const int ko = kk * 32 + l4 * 8;
    const bf8_t bfr = *reinterpret_cast<const bf8_t*>(&xw[nw + l15][ko]);
#pragma unroll
    for (int mi = 0; mi < 8; ++mi) {
      const bf8_t afr = *reinterpret_cast<const bf8_t*>(&Wc[mi * 16 + l15][ko]);
      acc[mi] = __builtin_amdgcn_mfma_f32_16x16x32_bf16(afr, bfr, acc[mi], 0, 0, 0);
    }
  }
  __syncthreads();
  // restage: rows n-d -> xw, Wc tap0
  const float* xpast = xbase - (size_t)d * 64;
  for (int r = 0; r < 4; ++r) {
    const int f4 = r * 256 + tid;
    const int row = f4 >> 4, c4 = (f4 & 15) << 2;
    const float4 v = *reinterpret_cast<const float4*>(xpast + row * 64 + c4);
    uint2 pp;
    pp.x = (unsigned)f2bu(v.x) | ((unsigned)f2bu(v.y) << 16);
    pp.y = (unsigned)f2bu(v.z) | ((unsigned)f2bu(v.w) << 16);
    *reinterpret_cast<uint2*>(&xw[row][c4]) = pp;
  }
  for (int r = 0; r < 8; ++r) {
    const int f4 = r * 256 + tid;
    const int row = f4 >> 4, c4 = (f4 & 15) << 2;
    *reinterpret_cast<uint2*>(&Wc[row][c4]) =
        *reinterpret_cast<const uint2*>(wcb + row * 64 + c4);
  }
  __syncthreads();
#pragma unroll
  for (int kk = 0; kk < 2; ++kk) {
    const int ko = kk * 32 + l4 * 8;
    const bf8_t bfr = *reinterpret_cast<const bf8_t*>(&xw[nw + l15][ko]);
#pragma unroll
    for (int mi = 0; mi < 8; ++mi) {
      const bf8_t afr = *reinterpret_cast<const bf8_t*>(&Wc[mi * 16 + l15][ko]);
      acc[mi] = __builtin_amdgcn_mfma_f32_16x16x32_bf16(afr, bfr, acc[mi], 0, 0, 0);
    }
  }

  // gate -> gt (bf16, [n][h])
  const int t_lane = t0 + nw + l15;
  const int ci = (t_lane >= (c0 + 1) * 75) ? 1 : 0;
#pragma unroll
  for (int mi = 0; mi < 4; ++mi) {
    float gg[4];
#pragma unroll
    for (int r = 0; r < 4; ++r) {
      const int olo = mi * 16 + l4 * 4 + r;
      const float ylo = acc[mi][r] + cnd[olo][ci];
      const float yhi = acc[mi + 4][r] + cnd[olo + 64][ci];
      gg[r] = tanhf(ylo) * (1.f / (1.f + expf(-yhi)));
    }
    const int hb = mi * 16 + l4 * 4;
    *reinterpret_cast<unsigned int*>(&gt[nw + l15][hb]) =
        (unsigned)f2bu(gg[0]) | ((unsigned)f2bu(gg[1]) << 16);
    *reinterpret_cast<unsigned int*>(&gt[nw + l15][hb + 2]) =
        (unsigned)f2bu(gg[2]) | ((unsigned)f2bu(gg[3]) << 16);
  }
  __syncthreads();

  // res GEMM from gt
  f4_t accr[4];
  if (write_x) {
#pragma unroll
    for (int i = 0; i < 4; ++i) accr[i] = (f4_t){0.f, 0.f, 0.f, 0.f};
#pragma unroll
    for (int kk = 0; kk < 2; ++kk) {
      const int ko = kk * 32 + l4 * 8;
      const bf8_t bfr = *reinterpret_cast<const bf8_t*>(&gt[nw + l15][ko]);
#pragma unroll
      for (int mi = 0; mi < 4; ++mi) {
        const bf8_t afr = *reinterpret_cast<const bf8_t*>(&Wr[mi * 16 + l15][ko]);
        accr[mi] = __builtin_amdgcn_mfma_f32_16x16x32_bf16(afr, bfr, accr[mi], 0, 0, 0);
      }
    }
  }
  // g -> gbuf[n][k] coalesced: 64 rows x 8 chunks = 512.
  unsigned short* grow = gbuf + (size_t)(b * kS + t0) * kK + layer * 64;
  for (int r = 0; r < 2; ++r) {
    const int ch = r * 256 + tid;
    const int row = ch >> 3, c8 = (ch & 7) << 3;
    *reinterpret_cast<uint4*>(grow + (size_t)row * kK + c8) =
        *reinterpret_cast<const uint4*>(&gt[row][c8]);
  }
  if (write_x) {
#pragma unroll
    for (int mi = 0; mi < 4; ++mi) {
#pragma unroll
      for (int r = 0; r < 4; ++r) {
        const int h2 = mi * 16 + l4 * 4 + r;
        xf[nw + l15][h2] = accr[mi][r] + rb[h2] + xf[nw + l15][h2];
      }
    }
    __syncthreads();
    float* xo = x_out + ((size_t)b * kXR + kGR + t0) * 64;
    for (int r = 0; r < 4; ++r) {
      const int f4 = r * 256 + tid;
      const int row = f4 >> 4, c4 = (f4 & 15) << 2;
      *reinterpret_cast<float4*>(xo + row * 64 + c4) =
          *reinterpret_cast<const float4*>(&xf[row][c4]);
    }
  }
}

// ---------------- stacked skip GEMM (MFMA): skipb[n][o] = g[n][:] . swb[o][:] + bs ----
__global__ __launch_bounds__(256) void skip_kernel(
    const unsigned short* __restrict__ gbuf, const unsigned short* __restrict__ swb,
    const float* __restrict__ bs, unsigned short* __restrict__ skipb) {
  const int n0 = blockIdx.x * 128, o0 = blockIdx.y * 128;
  __shared__ unsigned short Ag[128][kP];
  __shared__ unsigned short Bs[128][kP];
  const int tid = threadIdx.x, lane = tid & 63;
  const int wv = tid >> 6, wm = wv >> 1, wn = wv & 1;
  const int l15 = lane & 15, l4 = lane >> 4;
  f4_t acc[4][4];
#pragma unroll
  for (int i = 0; i < 4; ++i)
#pragma unroll
    for (int j = 0; j < 4; ++j) acc[i][j] = (f4_t){0.f, 0.f, 0.f, 0.f};
  for (int kb = 0; kb < 24; ++kb) {
    const int k0 = kb * 64;
    for (int r = 0; r < 4; ++r) {
      const int ch = r * 256 + tid;
      const int row = ch >> 3, c8 = (ch & 7) << 3;
      *reinterpret_cast<uint4*>(&Ag[row][c8]) =
          *reinterpret_cast<const uint4*>(gbuf + (size_t)(n0 + row) * kK + k0 + c8);
      *reinterpret_cast<uint4*>(&Bs[row][c8]) =
          *reinterpret_cast<const uint4*>(swb + (size_t)(o0 + row) * kK + k0 + c8);
    }
    __syncthreads();
#pragma unroll
    for (int kk = 0; kk < 2; ++kk) {
      const int ko = kk * 32 + l4 * 8;
      bf8_t afr[4], bfr[4];
#pragma unroll
      for (int i = 0; i < 4; ++i) {
        afr[i] = *reinterpret_cast<const bf8_t*>(&Ag[wm * 64 + i * 16 + l15][ko]);
        bfr[i] = *reinterpret_cast<const bf8_t*>(&Bs[wn * 64 + i * 16 + l15][ko]);
      }
#pragma unroll
      for (int mi = 0; mi < 4; ++mi)
#pragma unroll
        for (int ni = 0; ni < 4; ++ni)
          acc[mi][ni] = __builtin_amdgcn_mfma_f32_16x16x32_bf16(afr[mi], bfr[ni],
                                                                acc[mi][ni], 0, 0, 0);
    }
    __syncthreads();
  }
#pragma unroll
  for (int mi = 0; mi < 4; ++mi)
#pragma unroll
    for (int ni = 0; ni < 4; ++ni) {
      const int o = o0 + wn * 64 + ni * 16 + l15;
      const float bo = bs[o];
#pragma unroll
      for (int r = 0; r < 4; ++r) {
        const int n = n0 + wm * 64 + mi * 16 + l4 * 4 + r;
        skipb[(size_t)n * 256 + o] = f2bu(acc[mi][ni][r] + bo);
      }
    }
}

// ---------------- head: relu -> W1 -> relu -> W2 -> log_softmax ----------------
__device__ inline unsigned int relu2(unsigned int u) {
  const unsigned lo = (u & 0x8000u) ? 0u : (u & 0xFFFFu);
  const unsigned hi = (u & 0x80000000u) ? 0u : (u & 0xFFFF0000u);
  return lo | hi;
}

__global__ __launch_bounds__(256) void head_kernel(
    const unsigned short* __restrict__ skipb, const unsigned short* __restrict__ w1b,
    const unsigned short* __restrict__ w2b, float* __restrict__ out) {
  const int b = blockIdx.y;
  const int t0 = blockIdx.x * 32;
  const int n0 = b * kS + t0;
  __shared__ __align__(16) char smem[16896 * 2];
  __shared__ float lsa[32];
  unsigned short (*A1)[264] = reinterpret_cast<unsigned short(*)[264]>(smem);
  unsigned short (*H1)[264] = reinterpret_cast<unsigned short(*)[264]>(smem + 16896);
  float (*LG)[260] = reinterpret_cast<float(*)[260]>(smem);

  const int tid = threadIdx.x, lane = tid & 63, wv = tid >> 6;
  const int l15 = lane & 15, l4 = lane >> 4;
  for (int r = 0; r < 4; ++r) {
    const int ch = r * 256 + tid;
    const int row = ch >> 5, c8 = (ch & 31) << 3;
    uint4 v = *reinterpret_cast<const uint4*>(skipb + (size_t)(n0 + row) * 256 + c8);
    v.x = relu2(v.x); v.y = relu2(v.y); v.z = relu2(v.z); v.w = relu2(v.w);
    *reinterpret_cast<uint4*>(&A1[row][c8]) = v;
  }
  __syncthreads();
  f4_t a1[2][4];
#pragma unroll
  for (int i = 0; i < 2; ++i)
#pragma unroll
    for (int j = 0; j < 4; ++j) a1[i][j] = (f4_t){0.f, 0.f, 0.f, 0.f};
  for (int kk = 0; kk < 8; ++kk) {
    const int ko = kk * 32 + l4 * 8;
    bf8_t afr[2], bfr[4];
#pragma unroll
    for (int i = 0; i < 2; ++i)
      afr[i] = *reinterpret_cast<const bf8_t*>(&A1[i * 16 + l15][ko]);
#pragma unroll
    for (int j = 0; j < 4; ++j)
      bfr[j] = *reinterpret_cast<const bf8_t*>(w1b + (size_t)(wv * 64 + j * 16 + l15) * 256 + ko);
#pragma unroll
    for (int mi = 0; mi < 2; ++mi)
#pragma unroll
      for (int ni = 0; ni < 4; ++ni)
        a1[mi][ni] = __builtin_amdgcn_mfma_f32_16x16x32_bf16(afr[mi], bfr[ni],
                                                             a1[mi][ni], 0, 0, 0);
  }
#pragma unroll
  for (int mi = 0; mi < 2; ++mi)
#pragma unroll
    for (int ni = 0; ni < 4; ++ni)
#pragma unroll
      for (int r = 0; r < 4; ++r)
        H1[mi * 16 + l4 * 4 + r][wv * 64 + ni * 16 + l15] =
            f2bu(fmaxf(a1[mi][ni][r], 0.f));
  __syncthreads();
  f4_t a2[2][4];
#pragma unroll
  for (int i = 0; i < 2; ++i)
#pragma unroll
    for (int j = 0; j < 4; ++j) a2[i][j] = (f4_t){0.f, 0.f, 0.f, 0.f};
  for (int kk = 0; kk < 8; ++kk) {
    const int ko = kk * 32 + l4 * 8;
    bf8_t afr[2], bfr[4];
#pragma unroll
    for (int i = 0; i < 2; ++i)
      afr[i] = *reinterpret_cast<const bf8_t*>(&H1[i * 16 + l15][ko]);
#pragma unroll
    for (int j = 0; j < 4; ++j)
      bfr[j] = *reinterpret_cast<const bf8_t*>(w2b + (size_t)(wv * 64 + j * 16 + l15) * 256 + ko);
#pragma unroll
    for (int mi = 0; mi < 2; ++mi)
#pragma unroll
      for (int ni = 0; ni < 4; ++ni)
        a2[mi][ni] = __builtin_amdgcn_mfma_f32_16x16x32_bf16(afr[mi], bfr[ni],
                                                             a2[mi][ni], 0, 0, 0);
  }
  __syncthreads();  // all reads of A1/H1 done; LG overlays them
#pragma unroll
  for (int mi = 0; mi < 2; ++mi)
#pragma unroll
    for (int ni = 0; ni < 4; ++ni)
#pragma unroll
      for (int r = 0; r < 4; ++r)
        LG[mi * 16 + l4 * 4 + r][wv * 64 + ni * 16 + l15] = a2[mi][ni][r];
  __syncthreads();
  const int rn = tid >> 3, s = tid & 7;
  float m = -3.4e38f;
  for (int a = s; a < 256; a += 8) m = fmaxf(m, LG[rn][a]);
  m = fmaxf(m, __shfl_xor(m, 1));
  m = fmaxf(m, __shfl_xor(m, 2));
  m = fmaxf(m, __shfl_xor(m, 4));
  float sum = 0.f;
  for (int a = s; a < 256; a += 8) sum += expf(LG[rn][a] - m);
  sum += __shfl_xor(sum, 1);
  sum += __shfl_xor(sum, 2);
  sum += __shfl_xor(sum, 4);
  if (s == 0) lsa[rn] = m + logf(sum);
  __syncthreads();
  float* ob = out + (size_t)b * kA * kS + t0;
  for (int q = 0; q < 8; ++q) {
    const int a = q * 32 + (tid >> 3);
    const int t4 = (tid & 7) * 4;
    float4 v;
    v.x = LG[t4 + 0][a] - lsa[t4 + 0];
    v.y = LG[t4 + 1][a] - lsa[t4 + 1];
    v.z = LG[t4 + 2][a] - lsa[t4 + 2];
    v.w = LG[t4 + 3][a] - lsa[t4 + 3];
    *reinterpret_cast<float4*>(ob + (size_t)a * kS + t4) = v;
  }
}

}  // namespace

extern "C" void kernel_launch(void* const* d_in, const int* in_sizes, int n_in,
                              void* d_out, int out_size, void* d_ws, size_t ws_size,
                              hipStream_t stream) {
  const float* lf  = (const float*)d_in[0];
  const float* sig = (const float*)d_in[1];
  const float* ew  = (const float*)d_in[2];
  const float* eb  = (const float*)d_in[3];
  const float* tw  = (const float*)d_in[4];
  const float* tb  = (const float*)d_in[5];
  const float* cw  = (const float*)d_in[6];
  const float* cb  = (const float*)d_in[7];
  const float* dw  = (const float*)d_in[8];
  const float* dbf = (const float*)d_in[9];
  const float* rw  = (const float*)d_in[10];
  const float* rb  = (const float*)d_in[11];
  const float* sw  = (const float*)d_in[12];
  const float* sb  = (const float*)d_in[13];
  const float* w1  = (const float*)d_in[14];
  const float* w2  = (const float*)d_in[15];
  float* out = (float*)d_out;

  char* p = (char*)d_ws;
  float* cond = (float*)p;            p += (size_t)kB * 3072 * kT4 * 4;     // 6.29 MB
  float* xA = (float*)p;              p += (size_t)kB * kXR * kH * 4;       // 9.86 MB
  float* xB = (float*)p;              p += (size_t)kB * kXR * kH * 4;       // 9.86 MB
  unsigned short* gbuf = (unsigned short*)p;  p += (size_t)kB * kS * kK * 2;   // 118 MB
  unsigned short* skipb = (unsigned short*)p; p += (size_t)kB * kS * 256 * 2;  // 19.7 MB
  unsigned short* wcb = (unsigned short*)p;   p += (size_t)kNL * 2 * 128 * 64 * 2;
  unsigned short* wrb = (unsigned short*)p;   p += (size_t)(kNL - 1) * 64 * 64 * 2;
  unsigned short* swb = (unsigned short*)p;   p += (size_t)256 * kK * 2;
  unsigned short* w1b = (unsigned short*)p;   p += (size_t)256 * 256 * 2;
  unsigned short* w2b = (unsigned short*)p;   p += (size_t)256 * 256 * 2;
  float* bs = (float*)p;              p += 1024;

  prep_kernel<<<(1011712 + 255) / 256, 256, 0, stream>>>(dw, rw, sw, w1, w2,
                                                         wcb, wrb, swb, w1b, w2b);
  cond_kernel<<<dim3(256, 2), 128, 0, stream>>>(lf, tw, tb, cw, cb, dbf, cond);
  bias_sum_kernel<<<1, 256, 0, stream>>>(sb, bs);
  embed_kernel<<<(kB * kXR * kH + 255) / 256, 256, 0, stream>>>(sig, ew, eb, xA, xB);

  float* xcur = xA;
  float* xnxt = xB;
  for (int l = 0; l < kNL; ++l) {
    const int d = 1 << (l % 6);
    const int wx = (l < kNL - 1) ? 1 : 0;
    layer_kernel<<<dim3(300, 2), 256, 0, stream>>>(
        xcur, xnxt, wcb + (size_t)l * 16384, wrb + (size_t)(wx ? l : 0) * 4096,
        cond, rb + (size_t)(wx ? l : 0) * 64, gbuf, l, d, wx);
    if (wx) { float* tmp = xcur; xcur = xnxt; xnxt = tmp; }
  }
  skip_kernel<<<dim3(300, 2), 256, 0, stream>>>(gbuf, swb, bs, skipb);
  head_kernel<<<dim3(600, 2), 256, 0, stream>>>(skipb, w1b, w2b, out);
}